// Round 4
// baseline (271.569 us; speedup 1.0000x reference)
//
#include <hip/hip_runtime.h>

typedef unsigned short u16;
typedef __bf16 bf16x8 __attribute__((ext_vector_type(8)));
typedef float f32x16 __attribute__((ext_vector_type(16)));

__device__ __forceinline__ u16 f2bf(float f) {
    unsigned u = __builtin_bit_cast(unsigned, f);
    u += 0x7fffu + ((u >> 16) & 1u);
    return (u16)(u >> 16);
}

#define GLDS16(g, l) __builtin_amdgcn_global_load_lds( \
    (const __attribute__((address_space(1))) void*)(g), \
    (__attribute__((address_space(3))) void*)(l), 16, 0, 0)

#define QK_SCALE 0.044194173824159216f

// Fragment-tiled B layout: [N/32][K/16][lane 64][8], elem (n,k) at
//   ((n>>5)*(K/16) + (k>>4))*512 + ((n&31) + ((k>>3)&1)*32)*8 + (k&7)

// ---------------------------------------------------------------------------
// Weight conversion -> frag-tiled bf16.  Wqkv: [48][32][64][8], Wpb: [16][32][64][8]
// ---------------------------------------------------------------------------
__global__ __launch_bounds__(256) void convert_kernel(
    const float* __restrict__ Wq, const float* __restrict__ Wk,
    const float* __restrict__ Wv, const float* __restrict__ Wp,
    const float* __restrict__ bq, const float* __restrict__ bk,
    const float* __restrict__ bv,
    u16* __restrict__ Wqkv, u16* __restrict__ Wpb, float* __restrict__ bqkv)
{
    const int t = blockIdx.x * 256 + threadIdx.x;   // 512*256 = 131072
    const float* W;
    u16* dst;
    int n, k;
    float sc = 1.0f;
    if (t < 98304) {            // Wqkv frags
        const int nb = t >> 11, rem = t & 2047;
        const int kb = rem >> 6, ln = rem & 63;
        n = nb * 32 + (ln & 31);
        k = kb * 16 + (ln >> 5) * 8;
        if (n < 512)       { W = Wq; sc = QK_SCALE; }
        else if (n < 1024) { W = Wk; n -= 512; }
        else               { W = Wv; n -= 1024; }
        dst = Wqkv + (size_t)t * 8;
    } else {                    // Wpb frags
        const int t2 = t - 98304;
        const int nb = t2 >> 11, rem = t2 & 2047;
        const int kb = rem >> 6, ln = rem & 63;
        n = nb * 32 + (ln & 31);
        k = kb * 16 + (ln >> 5) * 8;
        W = Wp;
        dst = Wpb + (size_t)t2 * 8;
    }
    const float4 f0 = *(const float4*)(W + (size_t)n * 512 + k);
    const float4 f1 = *(const float4*)(W + (size_t)n * 512 + k + 4);
    u16 o[8] = {f2bf(f0.x * sc), f2bf(f0.y * sc), f2bf(f0.z * sc), f2bf(f0.w * sc),
                f2bf(f1.x * sc), f2bf(f1.y * sc), f2bf(f1.z * sc), f2bf(f1.w * sc)};
    *(uint4*)dst = *(const uint4*)o;

    if (t < 1536) {
        float bvv = (t < 512) ? bq[t] * QK_SCALE
                  : (t < 1024) ? bk[t & 511] : bv[t & 511];
        bqkv[t] = bvv;
    }
}

// ---------------------------------------------------------------------------
// GroupNorm: x [B,C,T] fp32 -> h_t [B,T,C] bf16 row-major.
// ---------------------------------------------------------------------------
__global__ __launch_bounds__(256) void gn_kernel(
    const float* __restrict__ x, const float* __restrict__ gamma,
    const float* __restrict__ beta, u16* __restrict__ ht)
{
    const int g = blockIdx.x, b = blockIdx.y, tid = threadIdx.x;
    const float* xg = x + ((size_t)b * 512 + (size_t)g * 16) * 1024;

    float s = 0.f, s2 = 0.f;
    const float4* x4 = (const float4*)xg;
    #pragma unroll 4
    for (int i = tid; i < 4096; i += 256) {
        float4 v = x4[i];
        s  += v.x + v.y + v.z + v.w;
        s2 += v.x * v.x + v.y * v.y + v.z * v.z + v.w * v.w;
    }
    #pragma unroll
    for (int off = 32; off; off >>= 1) {
        s  += __shfl_down(s, off);
        s2 += __shfl_down(s2, off);
    }
    __shared__ float rs[4], rs2[4];
    __shared__ float stat[2];
    const int w = tid >> 6;
    if ((tid & 63) == 0) { rs[w] = s; rs2[w] = s2; }
    __syncthreads();
    if (tid == 0) {
        float S  = rs[0] + rs[1] + rs[2] + rs[3];
        float S2 = rs2[0] + rs2[1] + rs2[2] + rs2[3];
        float mean = S * (1.f / 16384.f);
        float var  = S2 * (1.f / 16384.f) - mean * mean;
        stat[0] = mean;
        stat[1] = rsqrtf(var + 1e-5f);
    }
    __syncthreads();
    const float mean = stat[0], rstd = stat[1];

    float ga[16], be[16];
    #pragma unroll
    for (int ci = 0; ci < 16; ci++) {
        ga[ci] = gamma[g * 16 + ci];
        be[ci] = beta[g * 16 + ci];
    }
    for (int t = tid; t < 1024; t += 256) {
        u16 yv[16];
        #pragma unroll
        for (int ci = 0; ci < 16; ci++) {
            float v = xg[ci * 1024 + t];
            yv[ci] = f2bf((v - mean) * rstd * ga[ci] + be[ci]);
        }
        uint4* dst = (uint4*)(ht + ((size_t)b * 1024 + t) * 512 + g * 16);
        dst[0] = ((const uint4*)yv)[0];
        dst[1] = ((const uint4*)yv)[1];
    }
}

// ---------------------------------------------------------------------------
// Row softmax over frag-tiled bf16 P [b][32][64][64][8], in place.
// One wave per row t; lane l holds s = l*16..l*16+15 (two uint4 chunks).
// ---------------------------------------------------------------------------
__global__ __launch_bounds__(256) void softmax_kernel(u16* __restrict__ scores)
{
    const int row  = blockIdx.x * 4 + (threadIdx.x >> 6);
    const int lane = threadIdx.x & 63;
    const int b = row >> 10, t = row & 1023;
    u16* p = scores + (size_t)b * 1048576 +
             ((size_t)(t >> 5) * 64 + lane) * 512 + (t & 31) * 8;

    uint4 w0 = *(const uint4*)p;          // s = l*16 + 0..7
    uint4 w1 = *(const uint4*)(p + 256);  // s = l*16 + 8..15
    unsigned wd[8] = {w0.x, w0.y, w0.z, w0.w, w1.x, w1.y, w1.z, w1.w};
    float v[16];
    #pragma unroll
    for (int i = 0; i < 8; i++) {
        v[2 * i]     = __builtin_bit_cast(float, wd[i] << 16);
        v[2 * i + 1] = __builtin_bit_cast(float, wd[i] & 0xffff0000u);
    }
    float m = v[0];
    #pragma unroll
    for (int i = 1; i < 16; i++) m = fmaxf(m, v[i]);
    #pragma unroll
    for (int off = 1; off < 64; off <<= 1) m = fmaxf(m, __shfl_xor(m, off));

    float s = 0.f;
    #pragma unroll
    for (int i = 0; i < 16; i++) { v[i] = __expf(v[i] - m); s += v[i]; }
    #pragma unroll
    for (int off = 1; off < 64; off <<= 1) s += __shfl_xor(s, off);
    const float inv = 1.0f / s;

    #pragma unroll
    for (int i = 0; i < 8; i++) {
        unsigned lo = f2bf(v[2 * i] * inv);
        unsigned hi = f2bf(v[2 * i + 1] * inv);
        wd[i] = lo | (hi << 16);
    }
    *(uint4*)p         = make_uint4(wd[0], wd[1], wd[2], wd[3]);
    *(uint4*)(p + 256) = make_uint4(wd[4], wd[5], wd[6], wd[7]);
}

// ---------------------------------------------------------------------------
// Flat-B GEMM: C[m][n] = sum_k A[m][k]*B[n][k].
// A row-major (k-contiguous), staged via global_load_lds with dual-xor swizzle.
// B frag-tiled in global, loaded directly to VGPRs (no LDS).
// Block tile 256m x 128n, 4 waves (2x2), wave tile 128x64 = 4x2 frags of
// 32x32x16 MFMA.  BK=64.
// MODE 0: qkv  -> q frag-tiled; kt row-major [S,C]; v row-major [C,S]; +bias
// MODE 1: qk^T -> P frag-tiled [t][s] bf16
// MODE 2: pv   -> h2 row-major [T,C] bf16
// MODE 3: proj -> fp32 d_out[B,C,T] = acc + bias[n] + x
// ---------------------------------------------------------------------------
template <int MODE>
__global__ __launch_bounds__(256, 2) void gemm_flat(
    const u16* __restrict__ A, const u16* __restrict__ B,
    size_t strideA, size_t strideB, int lda, int Kd16, int K,
    u16* __restrict__ o0, u16* __restrict__ o1, u16* __restrict__ o2,
    float* __restrict__ fo, const float* __restrict__ bias,
    const float* __restrict__ xres)
{
    __shared__ u16 As[256 * 64];

    const int tid   = threadIdx.x;
    const int lane  = tid & 63;
    const int wave  = tid >> 6;
    const int wm    = (wave >> 1) * 128;
    const int wn    = (wave & 1) * 64;
    const int l31   = lane & 31;
    const int khalf = lane >> 5;
    const int b     = blockIdx.z;

    const u16* Ab = A + (size_t)b * strideA + (size_t)blockIdx.y * 256 * lda;
    const u16* Bb = B + (size_t)b * strideB;
    const int nb0 = blockIdx.x * 4 + (wave & 1) * 2;   // n-block32 base for wave

    // staging lanes: 8 rows x 8 chunks per GLDS
    const int srow = lane >> 3;     // 0..7 == r&7
    const int sc   = lane & 7;      // LDS slot
    // read-side swizzle key: distinct in every contiguous-8 and mod-4 lane group
    const int rkey = (l31 & 7) ^ ((l31 >> 2) & 7);

    f32x16 acc[4][2] = {};

    for (int k0 = 0; k0 < K; k0 += 64) {
        const int kb16 = k0 >> 4;
        __syncthreads();
        // B fragments for this iter: direct global->VGPR, 1KB coalesced each
        bf16x8 breg[4][2];
        #pragma unroll
        for (int kb = 0; kb < 4; kb++)
            #pragma unroll
            for (int j = 0; j < 2; j++)
                breg[kb][j] = *(const bf16x8*)(
                    Bb + ((size_t)(nb0 + j) * Kd16 + kb16 + kb) * 512 + lane * 8);
        // A staging: 8 GLDS per wave, 64 rows
        #pragma unroll
        for (int s = 0; s < 8; s++) {
            const int r = wave * 64 + s * 8 + srow;
            const int key = srow ^ ((2 * s + khalf) & 7);
            GLDS16(Ab + (size_t)r * lda + k0 + (sc ^ key) * 8,
                   As + r * 64 + sc * 8);
        }
        __syncthreads();

        #pragma unroll
        for (int kb = 0; kb < 4; kb++) {
            const int slot = ((kb * 2 + khalf) ^ rkey) * 8;
            bf16x8 af[4];
            #pragma unroll
            for (int i = 0; i < 4; i++)
                af[i] = *(const bf16x8*)(As + (wm + i * 32 + l31) * 64 + slot);
            #pragma unroll
            for (int i = 0; i < 4; i++)
                #pragma unroll
                for (int j = 0; j < 2; j++)
                    acc[i][j] = __builtin_amdgcn_mfma_f32_32x32x16_bf16(
                        af[i], breg[kb][j], acc[i][j], 0, 0, 0);
        }
    }

    // Epilogue. C/D: col = lane&31, row = (reg&3) + 8*(reg>>2) + 4*(lane>>5)
    const int mb = blockIdx.y * 256 + wm;          // + i*32 + 4*khalf + 8*g + r
    const int nbase = blockIdx.x * 128 + wn + l31; // + j*32

    #pragma unroll
    for (int i = 0; i < 4; i++) {
        #pragma unroll
        for (int j = 0; j < 2; j++) {
            const int n = nbase + j * 32;
            float bv = 0.f;
            if (MODE == 0 || MODE == 3) bv = bias[n];
            #pragma unroll
            for (int g = 0; g < 4; g++) {
                const int m0 = mb + i * 32 + 4 * khalf + 8 * g;
                const float a0 = acc[i][j][4 * g]     + bv;
                const float a1 = acc[i][j][4 * g + 1] + bv;
                const float a2 = acc[i][j][4 * g + 2] + bv;
                const float a3 = acc[i][j][4 * g + 3] + bv;
                if (MODE == 0) {
                    if (n < 512) {           // q -> frag-tiled [t][c], Kd16=32
                        const int c = n;
                        u16* qp = o0 + (size_t)b * 524288 +
                            ((size_t)((m0 >> 5)) * 32 + (c >> 4)) * 512 +
                            ((m0 & 31) + ((c >> 3) & 1) * 32) * 8 + (c & 7);
                        qp[0]  = f2bf(a0);
                        qp[8]  = f2bf(a1);
                        qp[16] = f2bf(a2);
                        qp[24] = f2bf(a3);
                    } else if (n < 1024) {   // kt row-major [S,C]
                        const int c = n - 512;
                        u16* kp = o1 + ((size_t)b * 1024 + m0) * 512 + c;
                        kp[0]    = f2bf(a0);
                        kp[512]  = f2bf(a1);
                        kp[1024] = f2bf(a2);
                        kp[1536] = f2bf(a3);
                    } else {                 // v row-major [C,S]
                        ushort4 hv = {f2bf(a0), f2bf(a1), f2bf(a2), f2bf(a3)};
                        *(ushort4*)(o2 + ((size_t)b * 512 + (n - 1024)) * 1024 + m0) = hv;
                    }
                } else if (MODE == 1) {      // P frag-tiled [t=n][s=m], Kd16=64
                    ushort4 hv = {f2bf(a0), f2bf(a1), f2bf(a2), f2bf(a3)};
                    u16* pp = o0 + (size_t)b * 1048576 +
                        ((size_t)(n >> 5) * 64 + (m0 >> 4)) * 512 +
                        ((n & 31) + (g & 1) * 32) * 8 + 4 * khalf;
                    *(ushort4*)pp = hv;
                } else if (MODE == 2) {      // h2 row-major [T=n, C=m]
                    ushort4 hv = {f2bf(a0), f2bf(a1), f2bf(a2), f2bf(a3)};
                    *(ushort4*)(o0 + ((size_t)b * 1024 + n) * 512 + m0) = hv;
                } else {                     // proj + bias + residual, [B,C,T]
                    const size_t off = ((size_t)b * 512 + n) * 1024 + m0;
                    const float4 xv = *(const float4*)(xres + off);
                    float4 ov = {a0 + xv.x, a1 + xv.y, a2 + xv.z, a3 + xv.w};
                    *(float4*)(fo + off) = ov;
                }
            }
        }
    }
}

// ---------------------------------------------------------------------------
extern "C" void kernel_launch(void* const* d_in, const int* in_sizes, int n_in,
                              void* d_out, int out_size, void* d_ws, size_t ws_size,
                              hipStream_t stream)
{
    const float* x     = (const float*)d_in[0];
    const float* gamma = (const float*)d_in[1];
    const float* beta  = (const float*)d_in[2];
    const float* Wq    = (const float*)d_in[3];
    const float* bq    = (const float*)d_in[4];
    const float* Wk    = (const float*)d_in[5];
    const float* bk    = (const float*)d_in[6];
    const float* Wv    = (const float*)d_in[7];
    const float* bv    = (const float*)d_in[8];
    const float* Wp    = (const float*)d_in[9];
    const float* bp    = (const float*)d_in[10];

    char* ws = (char*)d_ws;
    u16*   Wqkv   = (u16*)(ws + 0);           //  1,572,864 B (frag-tiled)
    u16*   Wpb    = (u16*)(ws + 1572864);     //    524,288 B (frag-tiled)
    float* bqkv   = (float*)(ws + 2097152);   //      8,192 B
    u16*   ht     = (u16*)(ws + 2105344);     // 16,777,216 B (reused as h2)
    u16*   kt     = (u16*)(ws + 18882560);    // 16,777,216 B
    u16*   vv     = (u16*)(ws + 35659776);    // 16,777,216 B
    u16*   scores = (u16*)(ws + 52436992);    // 33,554,432 B (frag-tiled P)
    u16*   qt  = (u16*)d_out;   // scratch: frag-tiled q (16.8MB of 33.5MB)
    u16*   h2  = ht;
    float* out = (float*)d_out;

    convert_kernel<<<512, 256, 0, stream>>>(Wq, Wk, Wv, Wp, bq, bk, bv,
                                            Wqkv, Wpb, bqkv);
    gn_kernel<<<dim3(32, 16), 256, 0, stream>>>(x, gamma, beta, ht);

    // GEMM1 qkv: M=1024(T) N=1536 K=512 ; A=ht[T,C], B=Wqkv frag (Kd16=32)
    gemm_flat<0><<<dim3(12, 4, 16), 256, 0, stream>>>(
        ht, Wqkv, 524288, 0, 512, 32, 512,
        qt, kt, vv, nullptr, bqkv, nullptr);

    // GEMM2 scores: M=1024(S) N=1024(T) K=512 ; A=kt[S,C], B=q frag (Kd16=32)
    gemm_flat<1><<<dim3(8, 4, 16), 256, 0, stream>>>(
        kt, qt, 524288, 524288, 512, 32, 512,
        scores, nullptr, nullptr, nullptr, nullptr, nullptr);

    softmax_kernel<<<4096, 256, 0, stream>>>(scores);

    // GEMM3 pv: M=512(C) N=1024(T) K=1024 ; A=v[C,S], B=P frag (Kd16=64)
    gemm_flat<2><<<dim3(8, 2, 16), 256, 0, stream>>>(
        vv, scores, 524288, 1048576, 1024, 64, 1024,
        h2, nullptr, nullptr, nullptr, nullptr, nullptr);

    // GEMM4 proj+res: M=1024(T) N=512 K=512 ; A=h2[T,C], B=Wpb frag (Kd16=32)
    gemm_flat<3><<<dim3(4, 4, 16), 256, 0, stream>>>(
        h2, Wpb, 524288, 0, 512, 32, 512,
        nullptr, nullptr, nullptr, out, bp, x);
}